// Round 11
// baseline (114.919 us; speedup 1.0000x reference)
//
#include <hip/hip_runtime.h>
#include <hip/hip_bf16.h>

// CustomAttention: proj = tanh(H @ W^T + b); scores = proj @ c; attn = softmax_L(scores);
// out0 = sum_l H * attn ; out1 = attn.   B=64, L=512, D=768.  M = B*L = 32768.
// Round 11: eliminate the convert_h pass (~150 MB HBM ~= 27 us).  The GEMM reads
// fp32 H directly: register-staged A (global float4 loads issued EARLY, cvt to
// f16 + swizzled ds_write LATE -> T14 issue-early/write-late split), B stays the
// proven f16 gload_lds path.  wsum reads fp32 H.  GEMM structure = r10 (128x128,
// BK=32, packed-pair conflict-free LDS, single barrier/step, XCD affinity).

using half8 = __attribute__((ext_vector_type(8))) _Float16;   // MFMA A/B frag (4 VGPRs)
using f32x4 = __attribute__((ext_vector_type(4))) float;      // MFMA C/D frag

#define AS1 __attribute__((address_space(1)))
#define AS3 __attribute__((address_space(3)))

__device__ __forceinline__ void gload_lds16(const void* g, void* l) {
  __builtin_amdgcn_global_load_lds((const AS1 void*)g, (AS3 void*)l, 16, 0, 0);
}

__device__ __forceinline__ unsigned short f2h(float x) {
  _Float16 h = (_Float16)x;                       // v_cvt_f16_f32, RNE
  return __builtin_bit_cast(unsigned short, h);
}

// tanh(x) = 1 - 2/(exp(2x)+1).
__device__ __forceinline__ float tanh_fast(float x) {
  return 1.0f - __fdividef(2.0f, 1.0f + __expf(2.0f * x));
}

// ---------------- W conversion (1.18 MB, ~0.5 us) ----------------
__global__ void convert_w(const float4* __restrict__ W4, ushort4* __restrict__ Wt) {
  int i = blockIdx.x * 256 + threadIdx.x;   // 147456 quads
  float4 x = W4[i];
  ushort4 o;
  o.x = f2h(x.x); o.y = f2h(x.y); o.z = f2h(x.z); o.w = f2h(x.w);
  Wt[i] = o;
}

// ---------------- GEMM (128x128, BK=32) + tanh/context epilogue ----------------
// LDS packed-pair 128-B rows (r8-r10 measured 0 conflicts):
//   tile row r in [0,128), k in [0,32): half=r>>6, lr=r&63, u'=half*4+(k>>3),
//   slot=u'^(lr&7), byte = lr*128 + slot*16 + (k&7)*2.
// B staged via gload_lds (linear dst, inverse-swizzled f16 source).
// A reg-staged from fp32 H: thread t owns (row=t>>1, khalf=t&1); 4 float4 loads,
// 16 cvt, 2 ds_write_b128 at the swizzled byte addrs (bijective, <=2-way banks).
// Grid: flat 1536; XCD decode (bid&7) keeps the 6 same-mtile blocks on one XCD.
__global__ __launch_bounds__(256) void gemm_scores(
    const float* __restrict__ H, const ushort* __restrict__ Wt,
    const float* __restrict__ bias, const float* __restrict__ cvec,
    float* __restrict__ part) {
  __shared__ ushort ldsA[2][4096];    // 2 x 8 KB
  __shared__ ushort ldsB[2][4096];    // 2 x 8 KB
  __shared__ float scpart[2][128];    // 1 KB  (total 33792 B -> 4 blocks/CU)

  const int tid = threadIdx.x;
  const int lane = tid & 63;
  const int wid = tid >> 6;           // 0..3
  const int wr = wid >> 1, wc = wid & 1;
  const int m = lane & 15, q = lane >> 4;

  const int bid = blockIdx.x;         // 0..1535
  const int xcd = bid & 7;
  const int slot = bid >> 3;          // 0..191
  const int mtile = xcd * 32 + slot / 6;
  const int ntile = slot % 6;

  const char* const Bbase = (const char*)Wt + (size_t)(ntile * 128) * 1536;

  // --- B staging source inverse (f16, as r10): thread t, chunk c writes LDS
  // byte c*4096 + t*16 -> lr=c*32+(t>>3), slot=t&7, u'=slot^((t>>3)&7)
  const int up = (tid & 7) ^ ((tid >> 3) & 7);
  const int lr_s = tid >> 3;
  const size_t src0 = (size_t)((up >> 2) * 64 + lr_s) * 1536 + (up & 3) * 16;
  const size_t src1 = (size_t)((up >> 2) * 64 + 32 + lr_s) * 1536 + (up & 3) * 16;
  const int wavebase = wid << 10;

  // --- A reg-staging geometry: row = t>>1 (0..127), khalf = t&1 ---
  const int arow = tid >> 1, kh = tid & 1;
  const float4* const asrc =
      (const float4*)(H + (size_t)(mtile * 128 + arow) * 768) + kh * 4;
  const int a_lr = arow & 63, a_half = arow >> 6;
  const int wbyte0 = a_lr * 128 + (((a_half * 4 + kh * 2 + 0) ^ (a_lr & 7)) << 4);
  const int wbyte1 = a_lr * 128 + (((a_half * 4 + kh * 2 + 1) ^ (a_lr & 7)) << 4);

  f32x4 acc[4][4];
  #pragma unroll
  for (int i = 0; i < 4; ++i)
    #pragma unroll
    for (int j = 0; j < 4; ++j)
      acc[i][j] = (f32x4){0.f, 0.f, 0.f, 0.f};

  // read-side swizzled byte offsets (identical to r10, measured 0 conflicts)
  const int aslot = ((wr * 4 + q) ^ (m & 7)) * 16;
  const int bslot = ((wc * 4 + q) ^ (m & 7)) * 16;

  auto cvt8 = [](float4 u, float4 v) -> half8 {
    half8 r;
    r[0] = (_Float16)u.x; r[1] = (_Float16)u.y;
    r[2] = (_Float16)u.z; r[3] = (_Float16)u.w;
    r[4] = (_Float16)v.x; r[5] = (_Float16)v.y;
    r[6] = (_Float16)v.z; r[7] = (_Float16)v.w;
    return r;
  };

  float4 a_in[4];
  #pragma unroll
  for (int c = 0; c < 4; ++c) a_in[c] = asrc[c];            // A(0) issue
  gload_lds16(Bbase + src0, (char*)ldsB[0] + wavebase);      // B(0)
  gload_lds16(Bbase + src1, (char*)ldsB[0] + 4096 + wavebase);
  *(half8*)((char*)ldsA[0] + wbyte0) = cvt8(a_in[0], a_in[1]);
  *(half8*)((char*)ldsA[0] + wbyte1) = cvt8(a_in[2], a_in[3]);
  __syncthreads();

  #pragma unroll
  for (int t = 0; t < 24; ++t) {
    const int cur = t & 1, nxt = cur ^ 1;
    if (t < 23) {
      #pragma unroll
      for (int c = 0; c < 4; ++c) a_in[c] = asrc[(t + 1) * 8 + c];   // issue early
      gload_lds16(Bbase + src0 + (t + 1) * 64, (char*)ldsB[nxt] + wavebase);
      gload_lds16(Bbase + src1 + (t + 1) * 64, (char*)ldsB[nxt] + 4096 + wavebase);
    }
    // compute step t (ds_read + 16 MFMA) while A(t+1)/B(t+1) are in flight
    {
      const char* Ab = (const char*)ldsA[cur];
      const char* Bb = (const char*)ldsB[cur];
      half8 areg[4], breg[4];
      #pragma unroll
      for (int mi = 0; mi < 4; ++mi)
        areg[mi] = *(const half8*)(Ab + (mi * 16 + m) * 128 + aslot);
      #pragma unroll
      for (int ni = 0; ni < 4; ++ni)
        breg[ni] = *(const half8*)(Bb + (ni * 16 + m) * 128 + bslot);
      #pragma unroll
      for (int mi = 0; mi < 4; ++mi)
        #pragma unroll
        for (int ni = 0; ni < 4; ++ni)
          acc[mi][ni] = __builtin_amdgcn_mfma_f32_16x16x32_f16(
              areg[mi], breg[ni], acc[mi][ni], 0, 0, 0);
    }
    if (t < 23) {   // write-late: a_in's vmcnt wait lands after the MFMA block
      *(half8*)((char*)ldsA[nxt] + wbyte0) = cvt8(a_in[0], a_in[1]);
      *(half8*)((char*)ldsA[nxt] + wbyte1) = cvt8(a_in[2], a_in[3]);
    }
    __syncthreads();
  }

  // epilogue: score partial = sum_e tanh(acc + b[e]) * c[e]
  float bb[4], cc[4];
  #pragma unroll
  for (int ni = 0; ni < 4; ++ni) {
    int e = ntile * 128 + wc * 64 + ni * 16 + m;
    bb[ni] = bias[e];
    cc[ni] = cvec[e];
  }
  #pragma unroll
  for (int mi = 0; mi < 4; ++mi) {
    #pragma unroll
    for (int j = 0; j < 4; ++j) {
      float s = 0.f;
      #pragma unroll
      for (int ni = 0; ni < 4; ++ni)
        s += tanh_fast(acc[mi][ni][j] + bb[ni]) * cc[ni];
      s += __shfl_xor(s, 1);
      s += __shfl_xor(s, 2);
      s += __shfl_xor(s, 4);
      s += __shfl_xor(s, 8);
      if (m == 0) scpart[wc][wr * 64 + mi * 16 + q * 4 + j] = s;
    }
  }
  __syncthreads();
  if (tid < 128)
    part[ntile * 32768 + mtile * 128 + tid] = scpart[0][tid] + scpart[1][tid];
}

// ---------------- fused softmax + weighted sum (fp32 H) ----------------
__global__ void wsum_fused(const float* __restrict__ H, const float* __restrict__ prt,
                           float* __restrict__ out) {
  int b = blockIdx.x, dc = blockIdx.y;   // grid (64,3), 128 threads
  int t = threadIdx.x;
  __shared__ float w[512];
  __shared__ float redm[2], reds[2];

  float s[4];
  #pragma unroll
  for (int i = 0; i < 4; ++i) {
    int r = b * 512 + t + i * 128;
    s[i] = prt[r] + prt[32768 + r] + prt[2 * 32768 + r] +
           prt[3 * 32768 + r] + prt[4 * 32768 + r] + prt[5 * 32768 + r];
  }
  float mx = fmaxf(fmaxf(s[0], s[1]), fmaxf(s[2], s[3]));
  #pragma unroll
  for (int o = 32; o >= 1; o >>= 1) mx = fmaxf(mx, __shfl_xor(mx, o));
  if ((t & 63) == 0) redm[t >> 6] = mx;
  __syncthreads();
  mx = fmaxf(redm[0], redm[1]);

  float e[4], sm = 0.f;
  #pragma unroll
  for (int i = 0; i < 4; ++i) { e[i] = __expf(s[i] - mx); sm += e[i]; }
  #pragma unroll
  for (int o = 32; o >= 1; o >>= 1) sm += __shfl_xor(sm, o);
  if ((t & 63) == 0) reds[t >> 6] = sm;
  __syncthreads();
  float inv = 1.0f / (reds[0] + reds[1]);
  #pragma unroll
  for (int i = 0; i < 4; ++i) w[t + i * 128] = e[i] * inv;
  __syncthreads();

  int d0 = dc * 256 + t * 2;
  const float2* hp = (const float2*)(H + (size_t)b * 512 * 768 + d0);
  float a0 = 0.f, a1 = 0.f;
  #pragma unroll 8
  for (int l = 0; l < 512; ++l) {
    float2 u = hp[(size_t)l * 384];
    float wl = w[l];
    a0 += wl * u.x;
    a1 += wl * u.y;
  }
  out[b * 768 + d0] = a0;
  out[b * 768 + d0 + 1] = a1;

  if (dc == 0) {
    #pragma unroll
    for (int i = 0; i < 4; ++i)
      out[49152 + b * 512 + t + i * 128] = w[t + i * 128];
  }
}

// ---------------- launch ----------------
extern "C" void kernel_launch(void* const* d_in, const int* in_sizes, int n_in,
                              void* d_out, int out_size, void* d_ws, size_t ws_size,
                              hipStream_t stream) {
  const float* H    = (const float*)d_in[0];   // [64,512,768] fp32
  const float* W    = (const float*)d_in[1];   // [768,768]
  const float* bias = (const float*)d_in[2];   // [768]
  const float* cvec = (const float*)d_in[3];   // [768,1]
  float* out = (float*)d_out;                  // [0,49152): weighted ; [49152,81920): attn

  char* ws = (char*)d_ws;
  ushort* Wt = (ushort*)(ws + 0);              // 1,179,648 B
  float*  prt = (float*)(ws + 1179648);        //   786,432 B ([6][32768])

  hipLaunchKernelGGL(convert_w, dim3(576), dim3(256), 0, stream,
                     (const float4*)W, (ushort4*)Wt);
  hipLaunchKernelGGL(gemm_scores, dim3(1536), dim3(256), 0, stream,
                     H, Wt, bias, cvec, prt);
  hipLaunchKernelGGL(wsum_fused, dim3(64, 3), dim3(128), 0, stream,
                     H, prt, out);
}

// Round 12
// 110.648 us; speedup vs baseline: 1.0386x; 1.0386x over previous
//
#include <hip/hip_runtime.h>
#include <hip/hip_bf16.h>

// CustomAttention: proj = tanh(H @ W^T + b); scores = proj @ c; attn = softmax_L(scores);
// out0 = sum_l H * attn ; out1 = attn.   B=64, L=512, D=768.  M = B*L = 32768.
// Round 12: r10 geometry (128x128, BK=32, 4 waves, packed-pair 0-conflict LDS,
// f16 gload_lds staging, XCD affinity) + DEPTH-2 prefetch: 3 LDS slots, stage
// tile t+2 each step, counted vmcnt(4) + lgkmcnt(0) + RAW s_barrier (ONE per
// step -- __syncthreads' implicit vmcnt(0) drain was nullifying all prefetch).

using half8 = __attribute__((ext_vector_type(8))) _Float16;   // MFMA A/B frag (4 VGPRs)
using f32x4 = __attribute__((ext_vector_type(4))) float;      // MFMA C/D frag

#define AS1 __attribute__((address_space(1)))
#define AS3 __attribute__((address_space(3)))

__device__ __forceinline__ void gload_lds16(const void* g, void* l) {
  __builtin_amdgcn_global_load_lds((const AS1 void*)g, (AS3 void*)l, 16, 0, 0);
}

__device__ __forceinline__ unsigned short f2h(float x) {
  _Float16 h = (_Float16)x;                       // v_cvt_f16_f32, RNE
  return __builtin_bit_cast(unsigned short, h);
}

// tanh(x) = 1 - 2/(exp(2x)+1).
__device__ __forceinline__ float tanh_fast(float x) {
  return 1.0f - __fdividef(2.0f, 1.0f + __expf(2.0f * x));
}

// ---------------- conversion kernels ----------------

__global__ void convert_h(const float4* __restrict__ H4, ushort4* __restrict__ Ah) {
  int i = blockIdx.x * 256 + threadIdx.x;   // 6291456 quads
  float4 x = H4[i];
  ushort4 o;
  o.x = f2h(x.x); o.y = f2h(x.y); o.z = f2h(x.z); o.w = f2h(x.w);
  Ah[i] = o;
}

__global__ void convert_w(const float4* __restrict__ W4, ushort4* __restrict__ Wt) {
  int i = blockIdx.x * 256 + threadIdx.x;   // 147456 quads
  float4 x = W4[i];
  ushort4 o;
  o.x = f2h(x.x); o.y = f2h(x.y); o.z = f2h(x.z); o.w = f2h(x.w);
  Wt[i] = o;
}

// ---------------- GEMM (128x128, BK=32, depth-2 pipeline) + epilogue ----------
// LDS packed-pair 128-B rows (r8-r10 measured 0 conflicts):
//   tile row r in [0,128), k in [0,32): half=r>>6, lr=r&63, u'=half*4+(k>>3),
//   slot=u'^(lr&7), byte = lr*128 + slot*16 + (k&7)*2.
// Staging: gload_lds linear dst, inverse-swizzled global source (both-sides).
// Pipeline ledger (4 loads A + ... per tile = 4 gload/wave):
//   step t: issue stage(t+2) [4 loads] ; compute(t) ; vmcnt(4) retires tile
//   t+1's loads (issued one full period earlier) ; lgkmcnt(0) ; s_barrier.
// Grid: flat 1536; XCD decode (bid&7) keeps the 6 same-mtile blocks on one XCD.
__global__ __launch_bounds__(256) void gemm_scores(
    const ushort* __restrict__ Ah, const ushort* __restrict__ Wt,
    const float* __restrict__ bias, const float* __restrict__ cvec,
    float* __restrict__ part) {
  __shared__ ushort ldsA[3][4096];    // 3 x 8 KB
  __shared__ ushort ldsB[3][4096];    // 3 x 8 KB
  __shared__ float scpart[2][128];    // 1 KB  (total 50176 B -> 3 blocks/CU)

  const int tid = threadIdx.x;
  const int lane = tid & 63;
  const int wid = tid >> 6;           // 0..3
  const int wr = wid >> 1, wc = wid & 1;
  const int m = lane & 15, q = lane >> 4;

  const int bid = blockIdx.x;         // 0..1535
  const int xcd = bid & 7;
  const int slot = bid >> 3;          // 0..191
  const int mtile = xcd * 32 + slot / 6;
  const int ntile = slot % 6;

  const char* const Abase = (const char*)Ah + (size_t)(mtile * 128) * 1536;
  const char* const Bbase = (const char*)Wt + (size_t)(ntile * 128) * 1536;

  // staging source inverse: thread t, chunk c writes LDS byte c*4096 + t*16
  //   lr = c*32 + (t>>3), slot = t&7, u' = slot ^ (lr&7)  (c*32 % 8 == 0)
  const int up = (tid & 7) ^ ((tid >> 3) & 7);
  const int lr_s = tid >> 3;          // 0..31
  const size_t src0 = (size_t)((up >> 2) * 64 + lr_s) * 1536 + (up & 3) * 16;
  const size_t src1 = (size_t)((up >> 2) * 64 + 32 + lr_s) * 1536 + (up & 3) * 16;
  const int wavebase = wid << 10;

  f32x4 acc[4][4];
  #pragma unroll
  for (int i = 0; i < 4; ++i)
    #pragma unroll
    for (int j = 0; j < 4; ++j)
      acc[i][j] = (f32x4){0.f, 0.f, 0.f, 0.f};

  auto stage = [&](int kt, int s) {
    gload_lds16(Abase + src0 + kt * 64, (char*)ldsA[s] + wavebase);
    gload_lds16(Abase + src1 + kt * 64, (char*)ldsA[s] + 4096 + wavebase);
    gload_lds16(Bbase + src0 + kt * 64, (char*)ldsB[s] + wavebase);
    gload_lds16(Bbase + src1 + kt * 64, (char*)ldsB[s] + 4096 + wavebase);
  };

  // read-side swizzled byte offsets (identical to r10, measured 0 conflicts)
  const int aslot = ((wr * 4 + q) ^ (m & 7)) * 16;
  const int bslot = ((wc * 4 + q) ^ (m & 7)) * 16;

  auto compute = [&](int s) {
    const char* Ab = (const char*)ldsA[s];
    const char* Bb = (const char*)ldsB[s];
    half8 areg[4], breg[4];
    #pragma unroll
    for (int mi = 0; mi < 4; ++mi)
      areg[mi] = *(const half8*)(Ab + (mi * 16 + m) * 128 + aslot);
    #pragma unroll
    for (int ni = 0; ni < 4; ++ni)
      breg[ni] = *(const half8*)(Bb + (ni * 16 + m) * 128 + bslot);
    __builtin_amdgcn_s_setprio(1);
    #pragma unroll
    for (int mi = 0; mi < 4; ++mi)
      #pragma unroll
      for (int ni = 0; ni < 4; ++ni)
        acc[mi][ni] = __builtin_amdgcn_mfma_f32_16x16x32_f16(
            areg[mi], breg[ni], acc[mi][ni], 0, 0, 0);
    __builtin_amdgcn_s_setprio(0);
  };

  // prologue: stage tiles 0,1 into slots 0,1 (wave's own 8 loads, oldest = tile0)
  stage(0, 0);
  stage(1, 1);
  asm volatile("s_waitcnt vmcnt(4)" ::: "memory");   // tile 0 landed
  __builtin_amdgcn_s_barrier();

  #pragma unroll
  for (int t = 0; t < 24; ++t) {
    if (t < 22) stage(t + 2, (t + 2) % 3);
    compute(t % 3);
    if (t < 22)       asm volatile("s_waitcnt vmcnt(4) lgkmcnt(0)" ::: "memory");
    else if (t == 22) asm volatile("s_waitcnt vmcnt(0) lgkmcnt(0)" ::: "memory");
    if (t < 23) __builtin_amdgcn_s_barrier();
  }

  // epilogue: score partial = sum_e tanh(acc + b[e]) * c[e]
  float bb[4], cc[4];
  #pragma unroll
  for (int ni = 0; ni < 4; ++ni) {
    int e = ntile * 128 + wc * 64 + ni * 16 + m;
    bb[ni] = bias[e];
    cc[ni] = cvec[e];
  }
  #pragma unroll
  for (int mi = 0; mi < 4; ++mi) {
    #pragma unroll
    for (int j = 0; j < 4; ++j) {
      float s = 0.f;
      #pragma unroll
      for (int ni = 0; ni < 4; ++ni)
        s += tanh_fast(acc[mi][ni][j] + bb[ni]) * cc[ni];
      s += __shfl_xor(s, 1);
      s += __shfl_xor(s, 2);
      s += __shfl_xor(s, 4);
      s += __shfl_xor(s, 8);
      if (m == 0) scpart[wc][wr * 64 + mi * 16 + q * 4 + j] = s;
    }
  }
  __syncthreads();
  if (tid < 128)
    part[ntile * 32768 + mtile * 128 + tid] = scpart[0][tid] + scpart[1][tid];
}

// ---------------- fused softmax + weighted sum ----------------
__global__ void wsum_fused(const ushort* __restrict__ Ah, const float* __restrict__ prt,
                           float* __restrict__ out) {
  int b = blockIdx.x, dc = blockIdx.y;   // grid (64,3), 128 threads
  int t = threadIdx.x;
  __shared__ float w[512];
  __shared__ float redm[2], reds[2];

  float s[4];
  #pragma unroll
  for (int i = 0; i < 4; ++i) {
    int r = b * 512 + t + i * 128;
    s[i] = prt[r] + prt[32768 + r] + prt[2 * 32768 + r] +
           prt[3 * 32768 + r] + prt[4 * 32768 + r] + prt[5 * 32768 + r];
  }
  float mx = fmaxf(fmaxf(s[0], s[1]), fmaxf(s[2], s[3]));
  #pragma unroll
  for (int o = 32; o >= 1; o >>= 1) mx = fmaxf(mx, __shfl_xor(mx, o));
  if ((t & 63) == 0) redm[t >> 6] = mx;
  __syncthreads();
  mx = fmaxf(redm[0], redm[1]);

  float e[4], sm = 0.f;
  #pragma unroll
  for (int i = 0; i < 4; ++i) { e[i] = __expf(s[i] - mx); sm += e[i]; }
  #pragma unroll
  for (int o = 32; o >= 1; o >>= 1) sm += __shfl_xor(sm, o);
  if ((t & 63) == 0) reds[t >> 6] = sm;
  __syncthreads();
  float inv = 1.0f / (reds[0] + reds[1]);
  #pragma unroll
  for (int i = 0; i < 4; ++i) w[t + i * 128] = e[i] * inv;
  __syncthreads();

  int d0 = dc * 256 + t * 2;
  const ushort* hp = Ah + (size_t)b * 512 * 768 + d0;
  float a0 = 0.f, a1 = 0.f;
  #pragma unroll 8
  for (int l = 0; l < 512; ++l) {
    unsigned u = *(const unsigned*)(hp + (size_t)l * 768);
    float wl = w[l];
    a0 += wl * (float)__builtin_bit_cast(_Float16, (unsigned short)(u & 0xffff));
    a1 += wl * (float)__builtin_bit_cast(_Float16, (unsigned short)(u >> 16));
  }
  out[b * 768 + d0] = a0;
  out[b * 768 + d0 + 1] = a1;

  if (dc == 0) {
    #pragma unroll
    for (int i = 0; i < 4; ++i)
      out[49152 + b * 512 + t + i * 128] = w[t + i * 128];
  }
}

// ---------------- launch ----------------
extern "C" void kernel_launch(void* const* d_in, const int* in_sizes, int n_in,
                              void* d_out, int out_size, void* d_ws, size_t ws_size,
                              hipStream_t stream) {
  const float* H    = (const float*)d_in[0];
  const float* W    = (const float*)d_in[1];
  const float* bias = (const float*)d_in[2];
  const float* cvec = (const float*)d_in[3];
  float* out = (float*)d_out;

  char* ws = (char*)d_ws;
  ushort* Ah = (ushort*)(ws + 0);              // 50,331,648 B
  ushort* Wt = (ushort*)(ws + 50331648);       //  1,179,648 B
  float*  prt = (float*)(ws + 51511296);       //    786,432 B ([6][32768])

  hipLaunchKernelGGL(convert_h, dim3(24576), dim3(256), 0, stream,
                     (const float4*)H, (ushort4*)Ah);
  hipLaunchKernelGGL(convert_w, dim3(576), dim3(256), 0, stream,
                     (const float4*)W, (ushort4*)Wt);
  hipLaunchKernelGGL(gemm_scores, dim3(1536), dim3(256), 0, stream,
                     Ah, Wt, bias, cvec, prt);
  hipLaunchKernelGGL(wsum_fused, dim3(64, 3), dim3(128), 0, stream,
                     Ah, prt, out);
}

// Round 13
// 105.402 us; speedup vs baseline: 1.0903x; 1.0498x over previous
//
#include <hip/hip_runtime.h>
#include <hip/hip_bf16.h>

// CustomAttention: proj = tanh(H @ W^T + b); scores = proj @ c; attn = softmax_L(scores);
// out0 = sum_l H * attn ; out1 = attn.   B=64, L=512, D=768.  M = B*L = 32768.
// Round 13: eliminate convert_h (~20 us) -- the GEMM stages A as fp32 via
// global_load_lds (linear dst, swizzled fp32 layout) and converts to f16 in
// registers after ds_read (identical RNE numerics).  Avoids r11's failure
// modes: no ds_write at all (conflicts), per-lane 16-B coalesced fp32 loads.
// GEMM otherwise = r12 (128x128, BK=32, 4 waves, depth-2 3-slot... simplified
// to r4-proven 2-slot dbuf at 49 KB -> 3 blocks/CU).  wsum reads fp32 H (exact).

using half8 = __attribute__((ext_vector_type(8))) _Float16;   // MFMA A/B frag (4 VGPRs)
using f32x4 = __attribute__((ext_vector_type(4))) float;      // MFMA C/D frag

#define AS1 __attribute__((address_space(1)))
#define AS3 __attribute__((address_space(3)))

__device__ __forceinline__ void gload_lds16(const void* g, void* l) {
  __builtin_amdgcn_global_load_lds((const AS1 void*)g, (AS3 void*)l, 16, 0, 0);
}

__device__ __forceinline__ unsigned short f2h(float x) {
  _Float16 h = (_Float16)x;                       // v_cvt_f16_f32, RNE
  return __builtin_bit_cast(unsigned short, h);
}

// tanh(x) = 1 - 2/(exp(2x)+1).
__device__ __forceinline__ float tanh_fast(float x) {
  return 1.0f - __fdividef(2.0f, 1.0f + __expf(2.0f * x));
}

// ---------------- W conversion (1.18 MB, ~0.5 us) ----------------
__global__ void convert_w(const float4* __restrict__ W4, ushort4* __restrict__ Wt) {
  int i = blockIdx.x * 256 + threadIdx.x;   // 147456 quads
  float4 x = W4[i];
  ushort4 o;
  o.x = f2h(x.x); o.y = f2h(x.y); o.z = f2h(x.z); o.w = f2h(x.w);
  Wt[i] = o;
}

// ---------------- GEMM (128x128, BK=32, fp32 A direct) + epilogue ----------
// A LDS layout (per slot, fp32): tile row r in [0,128) = one 128-B LDS row
// (32 floats).  float k at byte r*128 + ((k>>2)^(r&7))*16 + (k&3)*4.
//   gload staging: thread t, chunk c writes LDS byte c*4096 + t*16 ->
//   r = c*32 + (t>>3), unit u = (t&7)^((t>>3)&7); source = H + r*3072 +
//   kt*128 + u*16  (8 lanes/row cover 128 contiguous B -> coalesced).
//   read: frag (mi,q): 2 x b128 at slots (2q)^(m&7), (2q+1)^(m&7) -> slot =
//   perm(q)^(m&7), 8 lanes/slot -- isomorphic to the f16 pattern measured 0.
// B: f16 packed-pair layout + staging identical to r10/r12 (measured 0).
// Grid: flat 1536; XCD decode (bid&7) keeps the 6 same-mtile blocks on one XCD.
__global__ __launch_bounds__(256) void gemm_scores(
    const float* __restrict__ H, const ushort* __restrict__ Wt,
    const float* __restrict__ bias, const float* __restrict__ cvec,
    float* __restrict__ part) {
  __shared__ float  ldsA[2][4096];    // 2 x 16 KB (fp32 A)
  __shared__ ushort ldsB[2][4096];    // 2 x  8 KB (f16 B)
  __shared__ float scpart[2][128];    // 1 KB   (total 50176 B -> 3 blocks/CU)

  const int tid = threadIdx.x;
  const int lane = tid & 63;
  const int wid = tid >> 6;           // 0..3
  const int wr = wid >> 1, wc = wid & 1;
  const int m = lane & 15, q = lane >> 4;

  const int bid = blockIdx.x;         // 0..1535
  const int xcd = bid & 7;
  const int slot = bid >> 3;          // 0..191
  const int mtile = xcd * 32 + slot / 6;
  const int ntile = slot % 6;

  const char* const Abase = (const char*)(H + (size_t)(mtile * 128) * 768);
  const char* const Bbase = (const char*)Wt + (size_t)(ntile * 128) * 1536;

  // --- A staging source (fp32): thread t, chunk c -> r=c*32+tr3, u fixed ---
  const int tr3 = tid >> 3;                       // 0..31
  const int au = (tid & 7) ^ (tr3 & 7);           // unit 0..7 (c-independent)
  const size_t asrc0 = (size_t)tr3 * 3072 + au * 16;   // + c*98304 + kt*128

  // --- B staging source (f16 packed-pair, as r10/r12) ---
  const int up = (tid & 7) ^ (tr3 & 7);
  const size_t bsrc0 = (size_t)((up >> 2) * 64 + tr3) * 1536 + (up & 3) * 16;
  const size_t bsrc1 = (size_t)((up >> 2) * 64 + 32 + tr3) * 1536 + (up & 3) * 16;
  const int wavebase = wid << 10;

  f32x4 acc[4][4];
  #pragma unroll
  for (int i = 0; i < 4; ++i)
    #pragma unroll
    for (int j = 0; j < 4; ++j)
      acc[i][j] = (f32x4){0.f, 0.f, 0.f, 0.f};

  auto stage = [&](int kt, int s) {
    #pragma unroll
    for (int c = 0; c < 4; ++c)
      gload_lds16(Abase + asrc0 + (size_t)c * 98304 + kt * 128,
                  (char*)ldsA[s] + c * 4096 + wavebase);
    gload_lds16(Bbase + bsrc0 + kt * 64, (char*)ldsB[s] + wavebase);
    gload_lds16(Bbase + bsrc1 + kt * 64, (char*)ldsB[s] + 4096 + wavebase);
  };

  // read-side byte offsets
  const int aoff0 = ((2 * q) ^ (m & 7)) * 16;       // A slot c=0; c=1 is ^16
  const int bslot = ((wc * 4 + q) ^ (m & 7)) * 16;  // B (r10-identical)

  auto compute = [&](int s) {
    const char* Ab = (const char*)ldsA[s];
    const char* Bb = (const char*)ldsB[s];
    half8 areg[4], breg[4];
    #pragma unroll
    for (int mi = 0; mi < 4; ++mi) {
      int rowb = (wr * 64 + mi * 16 + m) * 128;
      f32x4 lo = *(const f32x4*)(Ab + rowb + aoff0);
      f32x4 hi = *(const f32x4*)(Ab + rowb + (aoff0 ^ 16));
      half8 r;
      r[0] = (_Float16)lo[0]; r[1] = (_Float16)lo[1];
      r[2] = (_Float16)lo[2]; r[3] = (_Float16)lo[3];
      r[4] = (_Float16)hi[0]; r[5] = (_Float16)hi[1];
      r[6] = (_Float16)hi[2]; r[7] = (_Float16)hi[3];
      areg[mi] = r;
    }
    #pragma unroll
    for (int ni = 0; ni < 4; ++ni)
      breg[ni] = *(const half8*)(Bb + (ni * 16 + m) * 128 + bslot);
    __builtin_amdgcn_s_setprio(1);
    #pragma unroll
    for (int mi = 0; mi < 4; ++mi)
      #pragma unroll
      for (int ni = 0; ni < 4; ++ni)
        acc[mi][ni] = __builtin_amdgcn_mfma_f32_16x16x32_f16(
            areg[mi], breg[ni], acc[mi][ni], 0, 0, 0);
    __builtin_amdgcn_s_setprio(0);
  };

  // --- dbuf loop: stage(t+1) | compute(t) | sync  (r4-proven) ---
  stage(0, 0);
  __syncthreads();
  #pragma unroll
  for (int t = 0; t < 24; ++t) {
    if (t < 23) stage(t + 1, (t + 1) & 1);
    compute(t & 1);
    __syncthreads();
  }

  // epilogue: score partial = sum_e tanh(acc + b[e]) * c[e]
  float bb[4], cc[4];
  #pragma unroll
  for (int ni = 0; ni < 4; ++ni) {
    int e = ntile * 128 + wc * 64 + ni * 16 + m;
    bb[ni] = bias[e];
    cc[ni] = cvec[e];
  }
  #pragma unroll
  for (int mi = 0; mi < 4; ++mi) {
    #pragma unroll
    for (int j = 0; j < 4; ++j) {
      float s = 0.f;
      #pragma unroll
      for (int ni = 0; ni < 4; ++ni)
        s += tanh_fast(acc[mi][ni][j] + bb[ni]) * cc[ni];
      s += __shfl_xor(s, 1);
      s += __shfl_xor(s, 2);
      s += __shfl_xor(s, 4);
      s += __shfl_xor(s, 8);
      if (m == 0) scpart[wc][wr * 64 + mi * 16 + q * 4 + j] = s;
    }
  }
  __syncthreads();
  if (tid < 128)
    part[ntile * 32768 + mtile * 128 + tid] = scpart[0][tid] + scpart[1][tid];
}

// ---------------- fused softmax + weighted sum (fp32 H, exact) ----------------
__global__ void wsum_fused(const float* __restrict__ H, const float* __restrict__ prt,
                           float* __restrict__ out) {
  int b = blockIdx.x, dc = blockIdx.y;   // grid (64,3), 128 threads
  int t = threadIdx.x;
  __shared__ float w[512];
  __shared__ float redm[2], reds[2];

  float s[4];
  #pragma unroll
  for (int i = 0; i < 4; ++i) {
    int r = b * 512 + t + i * 128;
    s[i] = prt[r] + prt[32768 + r] + prt[2 * 32768 + r] +
           prt[3 * 32768 + r] + prt[4 * 32768 + r] + prt[5 * 32768 + r];
  }
  float mx = fmaxf(fmaxf(s[0], s[1]), fmaxf(s[2], s[3]));
  #pragma unroll
  for (int o = 32; o >= 1; o >>= 1) mx = fmaxf(mx, __shfl_xor(mx, o));
  if ((t & 63) == 0) redm[t >> 6] = mx;
  __syncthreads();
  mx = fmaxf(redm[0], redm[1]);

  float e[4], sm = 0.f;
  #pragma unroll
  for (int i = 0; i < 4; ++i) { e[i] = __expf(s[i] - mx); sm += e[i]; }
  #pragma unroll
  for (int o = 32; o >= 1; o >>= 1) sm += __shfl_xor(sm, o);
  if ((t & 63) == 0) reds[t >> 6] = sm;
  __syncthreads();
  float inv = 1.0f / (reds[0] + reds[1]);
  #pragma unroll
  for (int i = 0; i < 4; ++i) w[t + i * 128] = e[i] * inv;
  __syncthreads();

  int d0 = dc * 256 + t * 2;
  const float2* hp = (const float2*)(H + (size_t)b * 512 * 768 + d0);
  float a0 = 0.f, a1 = 0.f;
  #pragma unroll 8
  for (int l = 0; l < 512; ++l) {
    float2 u = hp[(size_t)l * 384];
    float wl = w[l];
    a0 += wl * u.x;
    a1 += wl * u.y;
  }
  out[b * 768 + d0] = a0;
  out[b * 768 + d0 + 1] = a1;

  if (dc == 0) {
    #pragma unroll
    for (int i = 0; i < 4; ++i)
      out[49152 + b * 512 + t + i * 128] = w[t + i * 128];
  }
}

// ---------------- launch ----------------
extern "C" void kernel_launch(void* const* d_in, const int* in_sizes, int n_in,
                              void* d_out, int out_size, void* d_ws, size_t ws_size,
                              hipStream_t stream) {
  const float* H    = (const float*)d_in[0];   // [64,512,768] fp32
  const float* W    = (const float*)d_in[1];   // [768,768]
  const float* bias = (const float*)d_in[2];   // [768]
  const float* cvec = (const float*)d_in[3];   // [768,1]
  float* out = (float*)d_out;                  // [0,49152): weighted ; [49152,81920): attn

  char* ws = (char*)d_ws;
  ushort* Wt = (ushort*)(ws + 0);              // 1,179,648 B
  float*  prt = (float*)(ws + 1179648);        //   786,432 B ([6][32768])

  hipLaunchKernelGGL(convert_w, dim3(576), dim3(256), 0, stream,
                     (const float4*)W, (ushort4*)Wt);
  hipLaunchKernelGGL(gemm_scores, dim3(1536), dim3(256), 0, stream,
                     H, Wt, bias, cvec, prt);
  hipLaunchKernelGGL(wsum_fused, dim3(64, 3), dim3(128), 0, stream,
                     H, prt, out);
}